// Round 6
// baseline (408.200 us; speedup 1.0000x reference)
//
#include <hip/hip_runtime.h>

// ---------------------------------------------------------------------------
// QTranBase: twin 3-layer MLPs via bf16 MFMA.
// R12: full fusion. R6-R11 synthesis: every LDS-staged schedule variant
// pinned at MfmaUtil 24-27% (latency/barrier-bound, no pipe saturated), and
// the 3-kernel structure moves ~320MB of avoidable traffic (X prep 192MB,
// h1 round-trip 128MB). New structure: ONE fused kernel, 256 blocks x 8
// waves; block owns a 128-row stripe: L1Q -> L2Q+dot -> L1V -> L2V+dot.
// h1 (128x512 bf16 = 128KB) lives in LDS only. GEMM operands reg-loaded
// from global (L2-hot: weights 2.5MB total, X stripe 256KB) -> no staging,
// no K-loop barriers; 3 barriers per block total. h1 uses XOR-16B-unit
// swizzle (write: unit^=(row&7); read same) -> <=2-way conflicts.
// L3 dot: in-wave shfl reduce + atomicAdd into bias-seeded out.
// ---------------------------------------------------------------------------

#define ROWS 32768

using frag_ab = __attribute__((ext_vector_type(8))) short;   // 8 x bf16
using f32x4   = __attribute__((ext_vector_type(4))) float;   // MFMA C/D

__device__ __forceinline__ unsigned short f2bf(float f) {
    unsigned int u = __builtin_bit_cast(unsigned int, f);
    return (unsigned short)((u + 0x7fffu + ((u >> 16) & 1u)) >> 16);
}

__device__ __forceinline__ unsigned pk2rne(float lo, float hi) {
    return (unsigned)f2bf(lo) | ((unsigned)f2bf(hi) << 16);
}

// ---------------------------------------------------------------------------
// prep: [0,16384) convert X coalesced (R9-proven); [16384,16704) transpose
// weights via LDS tiles; [16704,16960) seed out with layer-3 bias.
// ---------------------------------------------------------------------------
__global__ __launch_bounds__(256)
void prep(const float* __restrict__ states, const float* __restrict__ actions,
          const float* __restrict__ Qw1, const float* __restrict__ Qw2,
          const float* __restrict__ Vw1, const float* __restrict__ Vw2,
          const float* __restrict__ qb3, const float* __restrict__ vb3,
          unsigned short* __restrict__ X,
          unsigned short* __restrict__ Qw1t, unsigned short* __restrict__ Qw2t,
          unsigned short* __restrict__ Vw1t, unsigned short* __restrict__ Vw2t,
          float* __restrict__ out) {
    const int b = blockIdx.x, tid = threadIdx.x;
    if (b < 16384) {
        int g = b * 256 + tid;
        int m = g >> 7, col = (g & 127) * 8;
        const float* src = (col < 512) ? states + (size_t)m * 512 + col
                                       : actions + (size_t)m * 512 + (col - 512);
        float4 f0 = ((const float4*)src)[0];
        float4 f1 = ((const float4*)src)[1];
        *(uint4*)(X + (size_t)m * 1024 + col) =
            make_uint4(pk2rne(f0.x, f0.y), pk2rne(f0.z, f0.w),
                       pk2rne(f1.x, f1.y), pk2rne(f1.z, f1.w));
    } else if (b < 16704) {
        __shared__ float T[64][65];
        int tg = b - 16384;
        const float* W; unsigned short* O; int Krows, kt, nt;
        if (tg < 128) { W = Qw1; O = Qw1t; Krows = 1024; kt = tg >> 3; nt = tg & 7; }
        else {
            tg -= 128; int seg = tg >> 6, r = tg & 63;
            kt = r >> 3; nt = r & 7; Krows = 512;
            W = (seg == 0) ? Qw2 : (seg == 1) ? Vw1 : Vw2;
            O = (seg == 0) ? Qw2t : (seg == 1) ? Vw1t : Vw2t;
        }
        const int k0 = kt * 64, n0 = nt * 64;
        const int rr = tid >> 4, c4 = (tid & 15) * 4;
#pragma unroll
        for (int p = 0; p < 4; ++p) {
            float4 v = *(const float4*)&W[(size_t)(k0 + p * 16 + rr) * 512 + n0 + c4];
            T[p * 16 + rr][c4]     = v.x;
            T[p * 16 + rr][c4 + 1] = v.y;
            T[p * 16 + rr][c4 + 2] = v.z;
            T[p * 16 + rr][c4 + 3] = v.w;
        }
        __syncthreads();
        const int n = tid >> 2, kc = (tid & 3) * 16;
        unsigned pk[8];
#pragma unroll
        for (int j = 0; j < 8; ++j)
            pk[j] = pk2rne(T[kc + 2 * j][n], T[kc + 2 * j + 1][n]);
        uint4* dst = (uint4*)(O + (size_t)(n0 + n) * Krows + k0 + kc);
        dst[0] = make_uint4(pk[0], pk[1], pk[2], pk[3]);
        dst[1] = make_uint4(pk[4], pk[5], pk[6], pk[7]);
    } else {
        int i = (b - 16704) * 256 + tid;
        out[i] = (i < ROWS) ? qb3[0] : vb3[0];
    }
}

// ---------------------------------------------------------------------------
// Fused L1+L2+L3. Block = 128-row stripe, 8 waves (im=wave>>2 in {0,1} owns
// 64 rows; in=wave&3 owns 64 cols per 256-col n-tile). Wave tile 64x64,
// acc[4][4] f32x4. All GEMM operands reg-loaded from global; h1 in LDS.
// ---------------------------------------------------------------------------
__global__ __launch_bounds__(512, 2)
void fused(const unsigned short* __restrict__ X,
           const unsigned short* __restrict__ Qw1t,
           const unsigned short* __restrict__ Vw1t,
           const float* __restrict__ Qb1, const float* __restrict__ Vb1,
           const unsigned short* __restrict__ Qw2t,
           const unsigned short* __restrict__ Vw2t,
           const float* __restrict__ Qb2, const float* __restrict__ Vb2,
           const float* __restrict__ Qw3, const float* __restrict__ Vw3,
           float* __restrict__ out) {
    __shared__ __align__(16) char h1[131072];   // 128 rows x 1KB (swizzled)
    const int tid = threadIdx.x, wave = tid >> 6, lane = tid & 63;
    const int im = wave >> 2, in = wave & 3;
    const int lrow = lane & 15, quad = lane >> 4;
    const int bid = blockIdx.x;
    const int mi = ((bid & 7) << 5) | (bid >> 3);   // bijective XCD swizzle
    const int bm = mi * 128;

    // ---- L1: h1 = relu(X[:, :K] @ Wt^T + bias), written to LDS ----
    auto l1 = [&](const unsigned short* Wt, int ldb, int NT, const float* bias) {
#pragma unroll 1
        for (int nt = 0; nt < 2; ++nt) {
            f32x4 acc[4][4] = {};
            const unsigned short* Ab =
                X + (size_t)(bm + im * 64 + lrow) * 1024 + quad * 8;
            const unsigned short* Bb =
                Wt + (size_t)(nt * 256 + in * 64 + lrow) * ldb + quad * 8;
#pragma unroll 2
            for (int kt = 0; kt < NT; ++kt) {
                frag_ab a[4][2], b[4][2];
#pragma unroll
                for (int i = 0; i < 4; ++i)
#pragma unroll
                    for (int s = 0; s < 2; ++s)
                        a[i][s] = *(const frag_ab*)(Ab + (size_t)i * 16 * 1024 +
                                                    kt * 64 + s * 32);
#pragma unroll
                for (int j = 0; j < 4; ++j)
#pragma unroll
                    for (int s = 0; s < 2; ++s)
                        b[j][s] = *(const frag_ab*)(Bb + (size_t)j * 16 * ldb +
                                                    kt * 64 + s * 32);
#pragma unroll
                for (int s = 0; s < 2; ++s)
#pragma unroll
                    for (int i = 0; i < 4; ++i)
#pragma unroll
                        for (int j = 0; j < 4; ++j)
                            acc[i][j] = __builtin_amdgcn_mfma_f32_16x16x32_bf16(
                                a[i][s], b[j][s], acc[i][j], 0, 0, 0);
            }
            // epilogue: bias + relu -> swizzled bf16 into h1
#pragma unroll
            for (int j = 0; j < 4; ++j) {
                const int col = nt * 256 + in * 64 + j * 16 + lrow;
                const float bc = bias[col];
#pragma unroll
                for (int i = 0; i < 4; ++i)
#pragma unroll
                    for (int r = 0; r < 4; ++r) {
                        float v = acc[i][j][r] + bc;
                        v = v > 0.0f ? v : 0.0f;
                        const int row = im * 64 + i * 16 + quad * 4 + r;
                        const int u = (col >> 3) ^ (row & 7);
                        *(unsigned short*)(h1 + row * 1024 + (u << 4) +
                                           (col & 7) * 2) = f2bf(v);
                    }
            }
        }
    };

    // ---- L2+L3: out[row] += sum_n relu(h1 @ W2^T + b2)[n] * w3[n] ----
    auto l2 = [&](const unsigned short* W2t, const float* b2,
                  const float* w3, float* op) {
        float ssum[4][4] = {};
#pragma unroll 1
        for (int nt = 0; nt < 2; ++nt) {
            f32x4 acc[4][4] = {};
            const unsigned short* Bb =
                W2t + (size_t)(nt * 256 + in * 64 + lrow) * 512 + quad * 8;
#pragma unroll 2
            for (int kt = 0; kt < 8; ++kt) {
                frag_ab a[4][2], b[4][2];
#pragma unroll
                for (int i = 0; i < 4; ++i)
#pragma unroll
                    for (int s = 0; s < 2; ++s) {
                        const int row = im * 64 + i * 16 + lrow;
                        const int u = (kt * 8 + s * 4 + quad) ^ (row & 7);
                        a[i][s] = *(const frag_ab*)(h1 + row * 1024 + (u << 4));
                    }
#pragma unroll
                for (int j = 0; j < 4; ++j)
#pragma unroll
                    for (int s = 0; s < 2; ++s)
                        b[j][s] = *(const frag_ab*)(Bb + (size_t)j * 16 * 512 +
                                                    kt * 64 + s * 32);
#pragma unroll
                for (int s = 0; s < 2; ++s)
#pragma unroll
                    for (int i = 0; i < 4; ++i)
#pragma unroll
                        for (int j = 0; j < 4; ++j)
                            acc[i][j] = __builtin_amdgcn_mfma_f32_16x16x32_bf16(
                                a[i][s], b[j][s], acc[i][j], 0, 0, 0);
            }
            float bc[4], wc[4];
#pragma unroll
            for (int j = 0; j < 4; ++j) {
                const int col = nt * 256 + in * 64 + j * 16 + lrow;
                bc[j] = b2[col];
                wc[j] = w3[col];
            }
#pragma unroll
            for (int i = 0; i < 4; ++i)
#pragma unroll
                for (int r = 0; r < 4; ++r) {
                    float s = 0.0f;
#pragma unroll
                    for (int j = 0; j < 4; ++j) {
                        float v = acc[i][j][r] + bc[j];
                        v = v > 0.0f ? v : 0.0f;
                        s += v * wc[j];
                    }
#pragma unroll
                    for (int m = 1; m < 16; m <<= 1) s += __shfl_xor(s, m, 64);
                    ssum[i][r] += s;
                }
        }
        if (lrow == 0) {
#pragma unroll
            for (int i = 0; i < 4; ++i)
#pragma unroll
                for (int r = 0; r < 4; ++r)
                    atomicAdd(&op[bm + im * 64 + i * 16 + quad * 4 + r],
                              ssum[i][r]);
        }
    };

    l1(Qw1t, 1024, 16, Qb1);
    __syncthreads();                 // h1Q fully written
    l2(Qw2t, Qb2, Qw3, out);
    __syncthreads();                 // h1Q reads done before V overwrites
    l1(Vw1t, 512, 8, Vb1);
    __syncthreads();                 // h1V fully written
    l2(Vw2t, Vb2, Vw3, out + ROWS);
}

extern "C" void kernel_launch(void* const* d_in, const int* in_sizes, int n_in,
                              void* d_out, int out_size, void* d_ws, size_t ws_size,
                              hipStream_t stream) {
    const float* states  = (const float*)d_in[0];
    const float* actions = (const float*)d_in[1];
    const float* Qw1 = (const float*)d_in[2];
    const float* Qb1 = (const float*)d_in[3];
    const float* Qw2 = (const float*)d_in[4];
    const float* Qb2 = (const float*)d_in[5];
    const float* Qw3 = (const float*)d_in[6];
    const float* Qb3 = (const float*)d_in[7];
    const float* Vw1 = (const float*)d_in[8];
    const float* Vb1 = (const float*)d_in[9];
    const float* Vw2 = (const float*)d_in[10];
    const float* Vb2 = (const float*)d_in[11];
    const float* Vw3 = (const float*)d_in[12];
    const float* Vb3 = (const float*)d_in[13];
    float* out = (float*)d_out;

    // workspace: X 64MB @0, transposed weights after
    char* ws = (char*)d_ws;
    unsigned short* X    = (unsigned short*)ws;
    unsigned short* Qw1t = (unsigned short*)(ws + 67108864);
    unsigned short* Qw2t = Qw1t + 512 * 1024;
    unsigned short* Vw1t = Qw2t + 512 * 512;
    unsigned short* Vw2t = Vw1t + 512 * 512;

    prep<<<dim3(16960), dim3(256), 0, stream>>>(states, actions, Qw1, Qw2, Vw1, Vw2,
                                                Qb3, Vb3, X, Qw1t, Qw2t, Vw1t, Vw2t, out);

    fused<<<dim3(256), dim3(512), 0, stream>>>(X, Qw1t, Vw1t, Qb1, Vb1,
                                               Qw2t, Vw2t, Qb2, Vb2, Qw3, Vw3, out);
}